// Round 13
// baseline (208.571 us; speedup 1.0000x reference)
//
#include <hip/hip_runtime.h>
#include <hip/hip_bf16.h>
#include <math.h>

// M=N=192, C=256, K=5, R=4096, POOL=2, TILES=3.
// Round-13 A/B (both experimental, attacking the ~10-12 cy/wave-load floor):
//  A) rcnn_head_lds4: block/ROI, 4 waves sample-split, float4 gather (1
//     pixel = 1 instruction), LDS sample buffer, then channel-per-thread
//     pool+FC.  576 -> 144 gather instrs per ROI, all independent.
//  B) rcnn_head_f2:   R1 structure with float2 (2ch/thread, 2 ROIs/block).
//     576 -> 288 gather instrs per ROI. Low risk; runs LAST, owns d_out.
constexpr int MH = 192;
constexpr int NH = 192;
constexpr int CH = 256;
constexpr int KH = 5;
constexpr int SS = 6;   // POOL*TILES
constexpr int TT = 3;   // TILES
constexpr int NXCD = 8;

// ---------- sort kernel: counting sort of ROIs by feature row py ----------
__global__ __launch_bounds__(256)
void roi_sort_kernel(const float* __restrict__ anchors, int R,
                     const int* __restrict__ field_p,
                     int* __restrict__ perm)
{
    __shared__ int offs[MH];
    const int t = threadIdx.x;
    const float field = (float)field_p[0];

    for (int i = t; i < MH; i += 256) offs[i] = 0;
    __syncthreads();
    for (int r = t; r < R; r += 256) {
        const float ay = anchors[4 * r + 1];
        int py = (int)((ay - field * 0.5f) / field);
        atomicAdd(&offs[py], 1);
    }
    __syncthreads();
    if (t == 0) {
        int acc = 0;
        for (int i = 0; i < MH; ++i) {
            int h = offs[i];
            offs[i] = acc;
            acc += h;
        }
    }
    __syncthreads();
    for (int r = t; r < R; r += 256) {
        const float ay = anchors[4 * r + 1];
        int py = (int)((ay - field * 0.5f) / field);
        int slot = atomicAdd(&offs[py], 1);
        perm[slot] = r;
    }
}

// ---------- shared per-ROI scalar prologue ----------
struct RoiState {
    float obj0, obj1, cx, cy, bw, bh;
    int   xi[SS], yi[SS];
    float wx[SS], wy[SS];
};

__device__ __forceinline__ void roi_prologue(
    const float* __restrict__ obj_out, const float* __restrict__ reg_out,
    const float* __restrict__ anchors, const int* __restrict__ anchor_px,
    float field, int r, RoiState& st)
{
    const float ax = anchors[r * 4 + 0];
    const float ay = anchors[r * 4 + 1];
    const float aw = anchors[r * 4 + 2];
    const float ah = anchors[r * 4 + 3];

    const int awi = (int)ah;
    int kk = 0;
#pragma unroll
    for (int i = 0; i < KH; ++i) {
        if (anchor_px[i] == awi) kk = i;
    }
    const int px = (int)((ax - field * 0.5f) / field);
    const int py = (int)((ay - field * 0.5f) / field);
    const int base = __builtin_amdgcn_readfirstlane((py * NH + px) * KH + kk);

    const float o0 = obj_out[base * 2 + 0];
    const float o1 = obj_out[base * 2 + 1];
    const float om = fmaxf(o0, o1);
    const float e0 = expf(o0 - om);
    const float e1 = expf(o1 - om);
    const float einv = 1.0f / (e0 + e1);
    st.obj0 = e0 * einv;
    st.obj1 = e1 * einv;

    const float rg0 = reg_out[base * 4 + 0];
    const float rg1 = reg_out[base * 4 + 1];
    const float rg2 = reg_out[base * 4 + 2];
    const float rg3 = reg_out[base * 4 + 3];
    st.cx = rg0 * aw + ax;
    st.cy = rg1 * ah + ay;
    st.bw = aw * expf(rg2);
    st.bh = ah * expf(rg3);

    const float x0f = st.cx - st.bw * 0.5f;
    const float y0f = st.cy - st.bh * 0.5f;
#pragma unroll
    for (int i = 0; i < SS; ++i) {
        const float off = (i + 0.5f) * (1.0f / SS);
        float fx = (x0f + off * st.bw) / field - 0.5f;
        float fl = floorf(fx);
        fl = fminf(fmaxf(fl, 0.0f), (float)(NH - 2));
        st.xi[i] = (int)fl;
        st.wx[i] = fminf(fmaxf(fx - fl, 0.0f), 1.0f);

        float fy = (y0f + off * st.bh) / field - 0.5f;
        float fy0 = floorf(fy);
        fy0 = fminf(fmaxf(fy0, 0.0f), (float)(MH - 2));
        st.yi[i] = (int)fy0;
        st.wy[i] = fminf(fmaxf(fy - fy0, 0.0f), 1.0f);
    }
}

// ---------- per-ROI tail box math + store (single thread) ----------
__device__ __forceinline__ void roi_store(
    float a0, float a1, float a2, float a3,
    const float* __restrict__ b_fc, const float* __restrict__ boxes,
    const RoiState& st, int r, float* __restrict__ out)
{
    a0 += b_fc[0]; a1 += b_fc[1]; a2 += b_fc[2]; a3 += b_fc[3];

    const float acx = a0 * st.bw + st.cx;
    const float acy = a1 * st.bh + st.cy;
    const float aww = st.bw * expf(a2);
    const float ahh = st.bh * expf(a3);

    const float gx = boxes[r * 4 + 0];
    const float gy = boxes[r * 4 + 1];
    const float gw = boxes[r * 4 + 2];
    const float gh = boxes[r * 4 + 3];
    const float txl = (gx + gw * 0.5f - st.cx) / st.bw;
    const float tyl = (gy + gh * 0.5f - st.cy) / st.bh;
    const float twl = logf(gw / st.bw);
    const float thl = logf(gh / st.bh);

    float* o = out + (size_t)r * 14;
    o[0]  = st.obj0; o[1]  = st.obj1;
    o[2]  = st.cx;   o[3]  = st.cy;  o[4]  = st.bw;  o[5]  = st.bh;
    o[6]  = acx;     o[7]  = acy;    o[8]  = aww;    o[9]  = ahh;
    o[10] = txl;     o[11] = tyl;    o[12] = twl;    o[13] = thl;
}

// ---------- VARIANT A: float4 sample-split gather via LDS ----------
__global__ __launch_bounds__(256, 4)
void rcnn_head_lds4(const float* __restrict__ features,
                    const float* __restrict__ obj_out,
                    const float* __restrict__ reg_out,
                    const float* __restrict__ anchors,
                    const float* __restrict__ boxes,
                    const float* __restrict__ W_fc,
                    const float* __restrict__ b_fc,
                    const int*   __restrict__ anchor_px,
                    const int*   __restrict__ field_p,
                    const int*   __restrict__ perm,
                    int chunk,
                    float*       __restrict__ out)
{
    const int b = blockIdx.x;
    const int rank = (b % NXCD) * chunk + (b / NXCD);
    const int r = perm ? perm[rank] : rank;
    const int tid = threadIdx.x;
    const int w = tid >> 6;      // wave 0..3
    const int l = tid & 63;      // lane
    const float field = (float)field_p[0];

    RoiState st;
    roi_prologue(obj_out, reg_out, anchors, anchor_px, field, r, st);

    __shared__ float smp[SS * SS][CH];   // 36 KiB sample buffer

    // ---- gather: wave w owns samples s with s%4==w; 1 pixel = 1 float4 load
#pragma unroll
    for (int k = 0; k < 9; ++k) {
        const int s = w + 4 * k;          // 0..35
        const int iy = s / SS, ix = s % SS;
        const int y0 = st.yi[iy], x0 = st.xi[ix];
        const float wxx = st.wx[ix], wyy = st.wy[iy];
        const int pix = __builtin_amdgcn_readfirstlane(y0 * NH + x0);
        const float* p00 = features + (size_t)pix * CH + 4 * l;
        const float4 v00 = *reinterpret_cast<const float4*>(p00);
        const float4 v01 = *reinterpret_cast<const float4*>(p00 + CH);
        const float4 v10 = *reinterpret_cast<const float4*>(p00 + NH * CH);
        const float4 v11 = *reinterpret_cast<const float4*>(p00 + NH * CH + CH);
        const float cwx = 1.0f - wxx, cwy = 1.0f - wyy;
        float4 sv;
        sv.x = cwy * (cwx * v00.x + wxx * v01.x) + wyy * (cwx * v10.x + wxx * v11.x);
        sv.y = cwy * (cwx * v00.y + wxx * v01.y) + wyy * (cwx * v10.y + wxx * v11.y);
        sv.z = cwy * (cwx * v00.z + wxx * v01.z) + wyy * (cwx * v10.z + wxx * v11.z);
        sv.w = cwy * (cwx * v00.w + wxx * v01.w) + wyy * (cwx * v10.w + wxx * v11.w);
        *reinterpret_cast<float4*>(&smp[s][4 * l]) = sv;
    }
    __syncthreads();

    // ---- pool + FC: thread per channel ----
    const int c = tid;
    float pooled[TT][TT];
#pragma unroll
    for (int ty = 0; ty < TT; ++ty) {
#pragma unroll
        for (int tx = 0; tx < TT; ++tx) {
            float mx = -INFINITY;
#pragma unroll
            for (int a = 0; a < 2; ++a)
#pragma unroll
                for (int d = 0; d < 2; ++d)
                    mx = fmaxf(mx, smp[(2 * ty + a) * SS + 2 * tx + d][c]);
            pooled[ty][tx] = mx;
        }
    }

    float s0 = 0.f, s1 = 0.f, s2 = 0.f, s3 = 0.f;
#pragma unroll
    for (int t = 0; t < TT * TT; ++t) {
        const float p = pooled[t / TT][t % TT];
        const float4 w4 = *reinterpret_cast<const float4*>(&W_fc[(size_t)(t * CH + c) * 4]);
        s0 += p * w4.x;
        s1 += p * w4.y;
        s2 += p * w4.z;
        s3 += p * w4.w;
    }
#pragma unroll
    for (int off = 32; off > 0; off >>= 1) {
        s0 += __shfl_down(s0, off);
        s1 += __shfl_down(s1, off);
        s2 += __shfl_down(s2, off);
        s3 += __shfl_down(s3, off);
    }

    __shared__ float red[4][4];
    if (l == 0) {
        red[w][0] = s0; red[w][1] = s1; red[w][2] = s2; red[w][3] = s3;
    }
    __syncthreads();
    if (c == 0) {
        roi_store(red[0][0] + red[1][0] + red[2][0] + red[3][0],
                  red[0][1] + red[1][1] + red[2][1] + red[3][1],
                  red[0][2] + red[1][2] + red[2][2] + red[3][2],
                  red[0][3] + red[1][3] + red[2][3] + red[3][3],
                  b_fc, boxes, st, r, out);
    }
}

// ---------- VARIANT B: float2 channels, 2 ROIs per block ----------
__global__ __launch_bounds__(256, 8)
void rcnn_head_f2(const float* __restrict__ features,
                  const float* __restrict__ obj_out,
                  const float* __restrict__ reg_out,
                  const float* __restrict__ anchors,
                  const float* __restrict__ boxes,
                  const float* __restrict__ W_fc,
                  const float* __restrict__ b_fc,
                  const int*   __restrict__ anchor_px,
                  const int*   __restrict__ field_p,
                  const int*   __restrict__ perm,
                  int chunk,           // (R/2)/NXCD
                  float*       __restrict__ out)
{
    const int b = blockIdx.x;                       // 0..R/2-1
    const int rank = (b % NXCD) * chunk + (b / NXCD);
    const int half = threadIdx.x >> 7;              // waves 0,1 -> 0; 2,3 -> 1
    const int r = perm ? perm[2 * rank + half] : (2 * rank + half);
    const int h = threadIdx.x & 127;                // channels 2h, 2h+1
    const float field = (float)field_p[0];

    RoiState st;
    roi_prologue(obj_out, reg_out, anchors, anchor_px, field, r, st);

    float2 pooled[TT][TT];
#pragma unroll
    for (int ty = 0; ty < TT; ++ty) {
#pragma unroll
        for (int tx = 0; tx < TT; ++tx) {
            float2 mx = make_float2(-INFINITY, -INFINITY);
#pragma unroll
            for (int sy = 0; sy < 2; ++sy) {
#pragma unroll
                for (int sx = 0; sx < 2; ++sx) {
                    const int iy = ty * 2 + sy;
                    const int ix = tx * 2 + sx;
                    const int pix = __builtin_amdgcn_readfirstlane(st.yi[iy] * NH + st.xi[ix]);
                    const float* p0 = features + (size_t)pix * CH + 2 * h;
                    const float2 v00 = *reinterpret_cast<const float2*>(p0);
                    const float2 v01 = *reinterpret_cast<const float2*>(p0 + CH);
                    const float2 v10 = *reinterpret_cast<const float2*>(p0 + NH * CH);
                    const float2 v11 = *reinterpret_cast<const float2*>(p0 + NH * CH + CH);
                    const float wxx = st.wx[ix];
                    const float wyy = st.wy[iy];
                    const float cwx = 1.0f - wxx, cwy = 1.0f - wyy;
                    const float vx = cwy * (cwx * v00.x + wxx * v01.x) + wyy * (cwx * v10.x + wxx * v11.x);
                    const float vy = cwy * (cwx * v00.y + wxx * v01.y) + wyy * (cwx * v10.y + wxx * v11.y);
                    mx.x = fmaxf(mx.x, vx);
                    mx.y = fmaxf(mx.y, vy);
                }
            }
            pooled[ty][tx] = mx;
        }
    }

    // FC: thread handles channels 2h and 2h+1
    float s0 = 0.f, s1 = 0.f, s2 = 0.f, s3 = 0.f;
#pragma unroll
    for (int t = 0; t < TT * TT; ++t) {
        const float2 p = pooled[t / TT][t % TT];
        const float* wr = &W_fc[(size_t)(t * CH + 2 * h) * 4];
        const float4 wa = *reinterpret_cast<const float4*>(wr);
        const float4 wb = *reinterpret_cast<const float4*>(wr + 4);
        s0 += p.x * wa.x + p.y * wb.x;
        s1 += p.x * wa.y + p.y * wb.y;
        s2 += p.x * wa.z + p.y * wb.z;
        s3 += p.x * wa.w + p.y * wb.w;
    }
#pragma unroll
    for (int off = 32; off > 0; off >>= 1) {
        s0 += __shfl_down(s0, off);
        s1 += __shfl_down(s1, off);
        s2 += __shfl_down(s2, off);
        s3 += __shfl_down(s3, off);
    }

    __shared__ float red[2][2][4];
    const int wave_in_half = (threadIdx.x >> 6) & 1;
    if ((threadIdx.x & 63) == 0) {
        red[half][wave_in_half][0] = s0;
        red[half][wave_in_half][1] = s1;
        red[half][wave_in_half][2] = s2;
        red[half][wave_in_half][3] = s3;
    }
    __syncthreads();
    if (h == 0) {   // tid 0 (half 0) and tid 128 (half 1)
        roi_store(red[half][0][0] + red[half][1][0],
                  red[half][0][1] + red[half][1][1],
                  red[half][0][2] + red[half][1][2],
                  red[half][0][3] + red[half][1][3],
                  b_fc, boxes, st, r, out);
    }
}

extern "C" void kernel_launch(void* const* d_in, const int* in_sizes, int n_in,
                              void* d_out, int out_size, void* d_ws, size_t ws_size,
                              hipStream_t stream) {
    const float* features  = (const float*)d_in[0];
    const float* obj_out   = (const float*)d_in[1];
    const float* reg_out   = (const float*)d_in[2];
    const float* anchors   = (const float*)d_in[3];
    const float* boxes     = (const float*)d_in[4];
    const float* W_fc      = (const float*)d_in[5];
    const float* b_fc      = (const float*)d_in[6];
    const int*   anchor_px = (const int*)d_in[7];
    const int*   field_p   = (const int*)d_in[8];
    float* out = (float*)d_out;

    const int R = in_sizes[3] / 4;   // anchors is (R,4)

    int* perm = nullptr;
    if (ws_size >= (size_t)R * sizeof(int) && (R % (2 * NXCD)) == 0) {
        perm = (int*)d_ws;
        roi_sort_kernel<<<dim3(1), dim3(256), 0, stream>>>(anchors, R, field_p, perm);
    }

    // A/B: experimental float4-LDS first, low-risk f2 LAST (owns d_out).
    rcnn_head_lds4<<<dim3(R), dim3(256), 0, stream>>>(
        features, obj_out, reg_out, anchors, boxes, W_fc, b_fc,
        anchor_px, field_p, perm, R / NXCD, out);
    rcnn_head_f2<<<dim3(R / 2), dim3(256), 0, stream>>>(
        features, obj_out, reg_out, anchors, boxes, W_fc, b_fc,
        anchor_px, field_p, perm, (R / 2) / NXCD, out);
}